// Round 6
// baseline (42.210 us; speedup 1.0000x reference)
//
#include <hip/hip_runtime.h>
#include <math.h>

#define B_TOTAL 2048
#define I_DIM   128
#define O_DIM   128
#define GK      68                  // G + k rows in w
#define NKNOT   71                  // G + 2k - 1
#define BT      64                  // b per block
#define BTILES  (B_TOTAL / BT)      // 32
#define RI      8                   // i per block
#define NR      (I_DIM / RI)        // 16 i-ranges
#define THREADS 512                 // 8 waves
#define SLICE_ELEMS (GK * O_DIM)    // 8704 bf16
#define SLICE_BYTES (SLICE_ELEMS * 2)       // 17408
#define CHUNKS  (SLICE_BYTES / 1024)        // 17 chunks (64 lanes x 16B)
#define W_ELEMS ((size_t)GK * I_DIM * O_DIM)        // 1114112
#define PART_FLOATS ((size_t)NR * B_TOTAL * O_DIM)  // 4M floats = 16MB
#define WS_FULL (PART_FLOATS * 4 + W_ELEMS * 2)     // ~18.2MB
#define WS_MIN  (W_ELEMS * 2)                       // 2.2MB

__device__ __forceinline__ float rdlanef(float v, int l) {
    return __int_as_float(__builtin_amdgcn_readlane(__float_as_int(v), l));
}
__device__ __forceinline__ unsigned short f2bf(float f) {   // RNE
    unsigned u = __float_as_uint(f);
    return (unsigned short)((u + 0x7fffu + ((u >> 16) & 1u)) >> 16);
}

// w (f32, [GK][I][O]) -> bf16 same layout. 1088 blocks x 256 thr, 4 elems/thr.
__global__ __launch_bounds__(256)
void wcvt(const float* __restrict__ w, unsigned short* __restrict__ wbf) {
    const int e4 = blockIdx.x * 256 + threadIdx.x;
    const float4 v = ((const float4*)w)[e4];
    ushort4 o;
    o.x = f2bf(v.x); o.y = f2bf(v.y); o.z = f2bf(v.z); o.w = f2bf(v.w);
    ((ushort4*)wbf)[e4] = o;
}

// grid = 32 b-tiles x 16 i-ranges = 512 blocks (2/CU), 512 threads (8 waves).
// Per i: stage bf16 w[:, i, :] (17.4KB) into LDS double-buffered.
// Per bl: lo half-wave reads rows g0,g0+2; hi half rows g0+1,g0+3 (2x
// ds_read_b64); coefs broadcast via readlane + per-half cndmask; silu row
// added by lo half only. Cross-half partial sums combined in epilogue.
template<bool USE_WS>
__global__ __launch_bounds__(THREADS, 4)
void flashkan_main(const float* __restrict__ x,
                   const unsigned short* __restrict__ wbf,
                   const float* __restrict__ t,
                   float* __restrict__ dst) {
    __shared__ unsigned short wbuf[2][SLICE_ELEMS];   // 2 x 17408 B
    __shared__ float t_sh[NKNOT];

    const int tid  = threadIdx.x;
    const int bid  = blockIdx.x;
    const int bt   = bid >> 4;      // 0..31
    const int r    = bid & 15;      // 0..15
    const int b0   = bt * BT;
    const int i0   = r * RI;
    const int wave = tid >> 6;
    const int lane = tid & 63;
    const int h    = lane >> 5;     // half-wave
    const int loff = (lane & 31) << 3;   // byte offset within a 256B row

    if (tid < NKNOT) t_sh[tid] = t[tid];
    __syncthreads();

    // ---- per-wave coef phase: lane owns (bl = lane>>3, ii = lane&7) ----
    float cf0, cf1, cf2, cf3, cf4;
    int   cg;
    {
        const int bl = lane >> 3;
        const int ii = lane & 7;
        const float xv = x[(size_t)(b0 + wave * 8 + bl) * I_DIM + (i0 + ii)];

        int ik = 3 + (int)floorf((xv + 1.0f) * 32.0f);
        ik = min(max(ik, 3), 66);
        while (ik < 66 && xv >= t_sh[ik + 1]) ++ik;
        while (ik > 3 && xv < t_sh[ik]) --ik;

        float l0, l1, l2, r0, r1, r2;
        float N0 = 1.0f, N1, N2, N3;
        l0 = xv - t_sh[ik];
        r0 = t_sh[ik + 1] - xv;
        {
            float temp = N0 / (r0 + l0);
            N0 = r0 * temp;
            N1 = l0 * temp;
        }
        l1 = xv - t_sh[ik - 1];
        r1 = t_sh[ik + 2] - xv;
        {
            float saved = 0.0f, temp;
            temp = N0 / (r0 + l1);
            N0 = saved + r0 * temp;
            saved = l1 * temp;
            temp = N1 / (r1 + l0);
            N1 = saved + r1 * temp;
            N2 = l0 * temp;
        }
        l2 = xv - t_sh[ik - 2];
        r2 = t_sh[ik + 3] - xv;
        {
            float saved = 0.0f, temp;
            temp = N0 / (r0 + l2);
            N0 = saved + r0 * temp;
            saved = l2 * temp;
            temp = N1 / (r1 + l1);
            N1 = saved + r1 * temp;
            saved = l1 * temp;
            temp = N2 / (r2 + l0);
            N2 = saved + r2 * temp;
            N3 = l0 * temp;
        }
        cf0 = N0; cf1 = N1; cf2 = N2; cf3 = N3;
        cf4 = xv / (1.0f + expf(-xv));
        cg  = ik - 3;
    }

    // ---- staging: bf16 slice w[:, i_abs, :] -> wbuf[sel] ----
    auto stage = [&](int sel, int i_abs) {
        for (int c = wave; c < CHUNKS; c += 8) {          // wave-uniform loop
            const int e = c * 512 + lane * 8;             // bf16 elem idx
            const int g = e >> 7;
            const int o = e & (O_DIM - 1);
            const unsigned short* src = wbf + ((size_t)g * I_DIM + i_abs) * O_DIM + o;
            void* dstp = (void*)((char*)&wbuf[sel][0] + c * 1024);  // uniform base
            __builtin_amdgcn_global_load_lds(
                (const __attribute__((address_space(1))) void*)src,
                (__attribute__((address_space(3))) void*)dstp,
                16, 0, 0);
        }
    };

    float4 acc[8];
    #pragma unroll
    for (int bl = 0; bl < 8; ++bl) acc[bl] = make_float4(0.f, 0.f, 0.f, 0.f);

    auto compute = [&](int ii, const unsigned short* buf) {
        const char* bufc = (const char*)buf;
        const uint2 u4 = *(const uint2*)(bufc + 67 * 256 + loff);   // silu row
        const float s0 = __uint_as_float(u4.x << 16);
        const float s1 = __uint_as_float(u4.x & 0xffff0000u);
        const float s2 = __uint_as_float(u4.y << 16);
        const float s3 = __uint_as_float(u4.y & 0xffff0000u);
        #pragma unroll
        for (int bl = 0; bl < 8; ++bl) {
            const int srcl = (bl << 3) | ii;              // owning lane (uniform)
            const float c0 = rdlanef(cf0, srcl);
            const float c1 = rdlanef(cf1, srcl);
            const float c2 = rdlanef(cf2, srcl);
            const float c3 = rdlanef(cf3, srcl);
            const float c4 = rdlanef(cf4, srcl);
            const int   g0 = __builtin_amdgcn_readlane(cg, srcl);

            const char* rp = bufc + ((g0 + h) << 8) + loff;
            const uint2 uA = *(const uint2*)rp;           // row g0+h
            const uint2 uB = *(const uint2*)(rp + 512);   // row g0+2+h

            const float cA  = h ? c1 : c0;
            const float cB  = h ? c3 : c2;
            const float c4h = h ? 0.0f : c4;

            float4& a = acc[bl];
            a.x += cA * __uint_as_float(uA.x << 16)
                 + cB * __uint_as_float(uB.x << 16)         + c4h * s0;
            a.y += cA * __uint_as_float(uA.x & 0xffff0000u)
                 + cB * __uint_as_float(uB.x & 0xffff0000u) + c4h * s1;
            a.z += cA * __uint_as_float(uA.y << 16)
                 + cB * __uint_as_float(uB.y << 16)         + c4h * s2;
            a.w += cA * __uint_as_float(uA.y & 0xffff0000u)
                 + cB * __uint_as_float(uB.y & 0xffff0000u) + c4h * s3;
        }
    };

    stage(0, i0);
    __syncthreads();   // slice 0 landed (compiler drains vmcnt at barrier)

    for (int iib = 0; iib < RI; iib += 2) {
        stage(1, i0 + iib + 1);                 // prefetch into buf 1
        compute(iib, wbuf[0]);
        __syncthreads();                        // buf1 landed, buf0 reads done
        if (iib + 2 < RI) stage(0, i0 + iib + 2);
        compute(iib + 1, wbuf[1]);
        __syncthreads();
    }

    // ---- epilogue: combine half-wave partials, store ----
    #pragma unroll
    for (int bl = 0; bl < 8; ++bl) {
        float4 a = acc[bl];
        a.x += __shfl(a.x, lane ^ 32);
        a.y += __shfl(a.y, lane ^ 32);
        a.z += __shfl(a.z, lane ^ 32);
        a.w += __shfl(a.w, lane ^ 32);
        const int b = b0 + wave * 8 + bl;
        if (lane < 32) {
            if (USE_WS) {
                float4* dp = (float4*)(dst + ((size_t)r * B_TOTAL + b) * O_DIM) + lane;
                *dp = a;
            } else {
                float* dp = dst + (size_t)b * O_DIM + lane * 4;
                atomicAdd(dp,     a.x);
                atomicAdd(dp + 1, a.y);
                atomicAdd(dp + 2, a.z);
                atomicAdd(dp + 3, a.w);
            }
        }
    }
}

// Reduce: out[b][o] = sum_r ws[r][b][o]
__global__ __launch_bounds__(256)
void flashkan_reduce(const float* __restrict__ ws, float* __restrict__ out) {
    const int f = blockIdx.x * 256 + threadIdx.x;       // < 65536
    const float4* base = (const float4*)ws + f;
    float4 s = make_float4(0.0f, 0.0f, 0.0f, 0.0f);
    #pragma unroll
    for (int r2 = 0; r2 < NR; ++r2) {
        const float4 v = base[(size_t)r2 * (B_TOTAL * O_DIM / 4)];
        s.x += v.x; s.y += v.y; s.z += v.z; s.w += v.w;
    }
    ((float4*)out)[f] = s;
}

extern "C" void kernel_launch(void* const* d_in, const int* in_sizes, int n_in,
                              void* d_out, int out_size, void* d_ws, size_t ws_size,
                              hipStream_t stream) {
    const float* x = (const float*)d_in[0];
    const float* w = (const float*)d_in[1];
    const float* t = (const float*)d_in[2];
    float* out = (float*)d_out;

    dim3 grid(BTILES * NR);     // 512 blocks = 2/CU
    dim3 block(THREADS);

    if (ws_size >= WS_FULL) {
        float* part = (float*)d_ws;
        unsigned short* wbf = (unsigned short*)((char*)d_ws + PART_FLOATS * 4);
        wcvt<<<(int)(W_ELEMS / 4 / 256), 256, 0, stream>>>(w, wbf);
        flashkan_main<true><<<grid, block, 0, stream>>>(x, wbf, t, part);
        flashkan_reduce<<<B_TOTAL * O_DIM / 4 / 256, 256, 0, stream>>>(part, out);
    } else {
        // fallback: atomic accumulation straight into out (still bf16 w)
        unsigned short* wbf = (unsigned short*)d_ws;    // needs 2.2MB
        hipMemsetAsync(out, 0, (size_t)out_size * sizeof(float), stream);
        wcvt<<<(int)(W_ELEMS / 4 / 256), 256, 0, stream>>>(w, wbf);
        flashkan_main<false><<<grid, block, 0, stream>>>(x, wbf, t, out);
    }
}

// Round 7
// 38.617 us; speedup vs baseline: 1.0930x; 1.0930x over previous
//
#include <hip/hip_runtime.h>
#include <math.h>

#define B_TOTAL 2048
#define I_DIM   128
#define O_DIM   128
#define GK      68                  // G + k rows in w
#define NKNOT   71                  // G + 2k - 1
#define BT      64                  // b per block
#define BTILES  (B_TOTAL / BT)      // 32
#define RI      8                   // i per block
#define NR      (I_DIM / RI)        // 16 i-ranges
#define THREADS 512                 // 8 waves
#define SLICE_FLOATS (GK * O_DIM)   // 8704 floats = 34816 B per i-slice
#define CHUNKS  (SLICE_FLOATS / 256)        // 34 chunks of 1KB (64 lanes x 16B)
#define WS_NEED ((size_t)NR * B_TOTAL * O_DIM * 4)   // 16 MB partials

__device__ __forceinline__ float rdlanef(float v, int l) {
    return __int_as_float(__builtin_amdgcn_readlane(__float_as_int(v), l));
}

// grid = 32 b-tiles x 16 i-ranges = 512 blocks (2/CU), 512 threads (8 waves).
// Coefs per-wave in registers (lane l owns bl=l>>3, ii=l&7), readlane bcast.
// Per i: stage f32 w[:, i, :] (34.8KB) into LDS double-buffered.
// Per bl: HALF-WAVE split — lo half reads rows g0,g0+2, hi half g0+1,g0+3,
// as 2x ds_read_b128 (each covers a full 512B row per half) -> half the DS
// issue slots / dependent loads of the float2 scheme. Silu row: same-address
// broadcast read, counted by lo half only. Halves combined via shfl(lane^32).
template<bool USE_WS>
__global__ __launch_bounds__(THREADS, 4)
void flashkan_main(const float* __restrict__ x,
                   const float* __restrict__ w,
                   const float* __restrict__ t,
                   float* __restrict__ dst) {
    __shared__ float wbuf[2][SLICE_FLOATS];     // 69632 B
    __shared__ float t_sh[NKNOT];

    const int tid  = threadIdx.x;
    const int bid  = blockIdx.x;
    const int bt   = bid >> 4;      // 0..31
    const int r    = bid & 15;      // 0..15
    const int b0   = bt * BT;
    const int i0   = r * RI;
    const int wave = tid >> 6;
    const int lane = tid & 63;
    const int h    = lane >> 5;     // half-wave: 0 -> rows g0,g0+2; 1 -> g0+1,g0+3
    const int l32  = lane & 31;

    if (tid < NKNOT) t_sh[tid] = t[tid];
    __syncthreads();

    // ---- per-wave coef phase: lane owns (bl = lane>>3, ii = lane&7) ----
    float cf0, cf1, cf2, cf3, cf4;
    int   cg;
    {
        const int bl = lane >> 3;
        const int ii = lane & 7;
        const float xv = x[(size_t)(b0 + wave * 8 + bl) * I_DIM + (i0 + ii)];

        int ik = 3 + (int)floorf((xv + 1.0f) * 32.0f);
        ik = min(max(ik, 3), 66);
        while (ik < 66 && xv >= t_sh[ik + 1]) ++ik;
        while (ik > 3 && xv < t_sh[ik]) --ik;

        float l0, l1, l2, r0, r1, r2;
        float N0 = 1.0f, N1, N2, N3;
        l0 = xv - t_sh[ik];
        r0 = t_sh[ik + 1] - xv;
        {
            float temp = N0 / (r0 + l0);
            N0 = r0 * temp;
            N1 = l0 * temp;
        }
        l1 = xv - t_sh[ik - 1];
        r1 = t_sh[ik + 2] - xv;
        {
            float saved = 0.0f, temp;
            temp = N0 / (r0 + l1);
            N0 = saved + r0 * temp;
            saved = l1 * temp;
            temp = N1 / (r1 + l0);
            N1 = saved + r1 * temp;
            N2 = l0 * temp;
        }
        l2 = xv - t_sh[ik - 2];
        r2 = t_sh[ik + 3] - xv;
        {
            float saved = 0.0f, temp;
            temp = N0 / (r0 + l2);
            N0 = saved + r0 * temp;
            saved = l2 * temp;
            temp = N1 / (r1 + l1);
            N1 = saved + r1 * temp;
            saved = l1 * temp;
            temp = N2 / (r2 + l0);
            N2 = saved + r2 * temp;
            N3 = l0 * temp;
        }
        cf0 = N0; cf1 = N1; cf2 = N2; cf3 = N3;
        cf4 = xv / (1.0f + expf(-xv));
        cg  = ik - 3;
    }

    // ---- staging: slice w[:, i_abs, :] -> wbuf[sel] ----
    auto stage = [&](int sel, int i_abs) {
        for (int c = wave; c < CHUNKS; c += 8) {          // wave-uniform loop
            const int f = c * 256 + lane * 4;
            const int g = f >> 7;
            const int o = f & (O_DIM - 1);
            const float* src = w + ((size_t)g * I_DIM + i_abs) * O_DIM + o;
            void* dstp = (void*)&wbuf[sel][c * 256];      // wave-uniform base
            __builtin_amdgcn_global_load_lds(
                (const __attribute__((address_space(1))) void*)src,
                (__attribute__((address_space(3))) void*)dstp,
                16, 0, 0);
        }
    };

    float4 acc[8];
    #pragma unroll
    for (int bl = 0; bl < 8; ++bl) acc[bl] = make_float4(0.f, 0.f, 0.f, 0.f);

    auto compute = [&](int ii, const float* buf) {
        // silu row (g=67): lanes l and l+32 read the same address (broadcast)
        const float4 sv = ((const float4*)(buf + 67 * O_DIM))[l32];
        #pragma unroll
        for (int bl = 0; bl < 8; ++bl) {
            const int srcl = (bl << 3) | ii;              // owning lane (uniform)
            const float c0 = rdlanef(cf0, srcl);
            const float c1 = rdlanef(cf1, srcl);
            const float c2 = rdlanef(cf2, srcl);
            const float c3 = rdlanef(cf3, srcl);
            const float c4 = rdlanef(cf4, srcl);
            const int   g0 = __builtin_amdgcn_readlane(cg, srcl);

            const float cA  = h ? c1 : c0;
            const float cB  = h ? c3 : c2;
            const float c4h = h ? 0.0f : c4;

            const float4* rp = (const float4*)(buf + (size_t)(g0 + h) * O_DIM) + l32;
            const float4 vA = rp[0];      // row g0+h
            const float4 vB = rp[64];     // row g0+2+h (2 rows = 64 float4)

            float4& a = acc[bl];
            a.x += cA * vA.x + cB * vB.x + c4h * sv.x;
            a.y += cA * vA.y + cB * vB.y + c4h * sv.y;
            a.z += cA * vA.z + cB * vB.z + c4h * sv.z;
            a.w += cA * vA.w + cB * vB.w + c4h * sv.w;
        }
    };

    stage(0, i0);
    __syncthreads();   // slice 0 landed (compiler drains vmcnt at barrier)

    for (int iib = 0; iib < RI; iib += 2) {
        stage(1, i0 + iib + 1);                 // prefetch into buf 1
        compute(iib, wbuf[0]);
        __syncthreads();                        // buf1 landed, buf0 reads done
        if (iib + 2 < RI) stage(0, i0 + iib + 2);
        compute(iib + 1, wbuf[1]);
        __syncthreads();
    }

    // ---- epilogue: combine half-wave partials, store (lo half) ----
    #pragma unroll
    for (int bl = 0; bl < 8; ++bl) {
        float4 a = acc[bl];
        a.x += __shfl(a.x, lane ^ 32);
        a.y += __shfl(a.y, lane ^ 32);
        a.z += __shfl(a.z, lane ^ 32);
        a.w += __shfl(a.w, lane ^ 32);
        const int b = b0 + wave * 8 + bl;
        if (lane < 32) {
            if (USE_WS) {
                float4* dp = (float4*)(dst + ((size_t)r * B_TOTAL + b) * O_DIM) + l32;
                *dp = a;
            } else {
                float* dp = dst + (size_t)b * O_DIM + l32 * 4;
                atomicAdd(dp,     a.x);
                atomicAdd(dp + 1, a.y);
                atomicAdd(dp + 2, a.z);
                atomicAdd(dp + 3, a.w);
            }
        }
    }
}

// Reduce: out[b][o] = sum_r ws[r][b][o]
__global__ __launch_bounds__(256)
void flashkan_reduce(const float* __restrict__ ws, float* __restrict__ out) {
    const int f = blockIdx.x * 256 + threadIdx.x;       // < 65536
    const float4* base = (const float4*)ws + f;
    float4 s = make_float4(0.0f, 0.0f, 0.0f, 0.0f);
    #pragma unroll
    for (int r2 = 0; r2 < NR; ++r2) {
        const float4 v = base[(size_t)r2 * (B_TOTAL * O_DIM / 4)];
        s.x += v.x; s.y += v.y; s.z += v.z; s.w += v.w;
    }
    ((float4*)out)[f] = s;
}

extern "C" void kernel_launch(void* const* d_in, const int* in_sizes, int n_in,
                              void* d_out, int out_size, void* d_ws, size_t ws_size,
                              hipStream_t stream) {
    const float* x = (const float*)d_in[0];
    const float* w = (const float*)d_in[1];
    const float* t = (const float*)d_in[2];
    float* out = (float*)d_out;

    dim3 grid(BTILES * NR);     // 512 blocks = 2/CU
    dim3 block(THREADS);

    if (ws_size >= WS_NEED) {
        float* ws = (float*)d_ws;
        flashkan_main<true><<<grid, block, 0, stream>>>(x, w, t, ws);
        flashkan_reduce<<<B_TOTAL * O_DIM / 4 / 256, 256, 0, stream>>>(ws, out);
    } else {
        hipMemsetAsync(out, 0, (size_t)out_size * sizeof(float), stream);
        flashkan_main<false><<<grid, block, 0, stream>>>(x, w, t, out);
    }
}